// Round 6
// baseline (237.657 us; speedup 1.0000x reference)
//
#include <hip/hip_runtime.h>
#include <hip/hip_bf16.h>
#include <stdint.h>

// Shape fixed by reference: B=2, S=1024 -> M=2048; N=4096; K=4096
#define M_DIM 2048
#define N_DIM 4096
#define K_DIM 4096

#define BM 128
#define BN 128
#define BK 128            // int8 elems per K-tile = 128 B per row

#define ATILE (BM * BK)   // 16 KiB per A buffer
#define BTILE (BN * BK)   // 16 KiB per B buffer

typedef __attribute__((ext_vector_type(4))) int int4v;

// ---------- x: fp32 [M,K] -> int8 per-row dynamic quant; sx[row] = rowmax/127 ----------
__global__ __launch_bounds__(256) void quant_x(const float* __restrict__ x,
                                               int8_t* __restrict__ Aq,
                                               float* __restrict__ sx) {
    const int row = blockIdx.x;
    const int tid = threadIdx.x;
    const float4* xr = (const float4*)(x + (size_t)row * K_DIM);

    float4 v[4];
    float mx = 0.f;
#pragma unroll
    for (int p = 0; p < 4; p++) {
        v[p] = xr[p * 256 + tid];
        mx = fmaxf(mx, fmaxf(fmaxf(fabsf(v[p].x), fabsf(v[p].y)),
                             fmaxf(fabsf(v[p].z), fabsf(v[p].w))));
    }
#pragma unroll
    for (int off = 32; off >= 1; off >>= 1)
        mx = fmaxf(mx, __shfl_xor(mx, off, 64));

    __shared__ float wmax[4];
    __shared__ float smax;
    if ((tid & 63) == 0) wmax[tid >> 6] = mx;
    __syncthreads();
    if (tid == 0) {
        float m = fmaxf(fmaxf(wmax[0], wmax[1]), fmaxf(wmax[2], wmax[3]));
        m = fmaxf(m, 1e-20f);
        smax = m;
        sx[row] = m * (1.0f / 127.0f);
    }
    __syncthreads();
    const float inv = 127.0f / smax;

    int* out = (int*)Aq + (size_t)row * (K_DIM / 4);
#pragma unroll
    for (int p = 0; p < 4; p++) {
        int q0 = (int)__builtin_rintf(v[p].x * inv);
        int q1 = (int)__builtin_rintf(v[p].y * inv);
        int q2 = (int)__builtin_rintf(v[p].z * inv);
        int q3 = (int)__builtin_rintf(v[p].w * inv);
        q0 = max(-127, min(127, q0)); q1 = max(-127, min(127, q1));
        q2 = max(-127, min(127, q2)); q3 = max(-127, min(127, q3));
        out[p * 256 + tid] = (q0 & 255) | ((q1 & 255) << 8) |
                             ((q2 & 255) << 16) | ((q3 & 255) << 24);
    }
}

// ---------- w: int32 [N,K] (values in [-128,127]) -> int8 (low-byte, exact) ----------
__global__ __launch_bounds__(256) void cvt_w8(const int* __restrict__ w,
                                              int8_t* __restrict__ Bq) {
    size_t i = ((size_t)blockIdx.x * 256 + threadIdx.x) * 16;
    int4 a0 = *(const int4*)(w + i);
    int4 a1 = *(const int4*)(w + i + 4);
    int4 a2 = *(const int4*)(w + i + 8);
    int4 a3 = *(const int4*)(w + i + 12);
    uint4 t;
    t.x = (a0.x & 255) | ((a0.y & 255) << 8) | ((a0.z & 255) << 16) | ((a0.w & 255) << 24);
    t.y = (a1.x & 255) | ((a1.y & 255) << 8) | ((a1.z & 255) << 16) | ((a1.w & 255) << 24);
    t.z = (a2.x & 255) | ((a2.y & 255) << 8) | ((a2.z & 255) << 16) | ((a2.w & 255) << 24);
    t.w = (a3.x & 255) | ((a3.y & 255) << 8) | ((a3.z & 255) << 16) | ((a3.w & 255) << 24);
    *(uint4*)(Bq + i) = t;
}

// ---------- GEMM: C = Aq[M,K] x Bq[N,K]^T (i8 MFMA, i32 acc), dequant epilogue ----------
// Round-6 structure (r4 was LDS-BW-bound at ~256 KiB/CU-iter):
//  * 256 thr = 4 waves in 2x2; wave tile 64x64 = acc[4][4] of 16x16x64 i8.
//    4x fragment reuse both sides -> frag reads 64 KiB (was 96) per block-iter.
//  * Register-bridge staging: plain global_load -> VGPR -> ds_write (replaces
//    glds). Plain loads have no LDS-visibility requirement, so they remain in
//    flight ACROSS __syncthreads; the vmcnt wait attaches to the ds_write one
//    full iteration after issue (~2000 cyc flight >> 900-cyc HBM latency).
//    Removes the structural vmcnt(0)-at-barrier drain of global_load_lds.
//  * Dbuf LDS 2x(16+16) KiB = 64 KiB -> 2 blocks/CU (r5 proved 1/CU regresses).
//  * XOR swizzle (phys_cg = log_cg ^ (row&7)) on both ds_write addressing and
//    frag reads; bank conflicts measured 0 in r2-r5 with this scheme.
//  * A/B fragments share the per-lane byte pattern -> lane->k permutation inside
//    the i8 MFMA cancels; only the shape-determined C/D layout matters.

__global__ __launch_bounds__(256, 2) void gemm_bt_i8(
    const int8_t* __restrict__ A,      // [M,K] int8
    const int8_t* __restrict__ B,      // [N,K] int8
    const float*  __restrict__ sx,     // [M] row dequant scale
    const float*  __restrict__ scales, // [N]
    const float*  __restrict__ bias,   // [N]
    float* __restrict__ C)             // [M,N]
{
    __shared__ __align__(16) int8_t As[2 * ATILE];  // 32 KiB
    __shared__ __align__(16) int8_t Bs[2 * BTILE];  // 32 KiB

    const int tid  = threadIdx.x;
    const int bm   = blockIdx.y;
    const int bn   = blockIdx.x;
    const int lane = tid & 63;
    const int wave = tid >> 6;           // 0..3
    const int wm   = (wave >> 1) * 64;   // 0 or 64
    const int wn   = (wave & 1) * 64;    // 0 or 64
    const int l16  = lane & 15;
    const int quad = lane >> 4;
    const int swz  = l16 & 7;

    // Staging map: 4 loads per tile; load p covers rows p*32+srow (srow=tid>>3),
    // 16 B at logical colgroup cgl = cgp ^ (row&7), cgp = tid&7. Since p*32 is
    // 0 mod 8, cgl is uniform across p. LDS write addr = p*4096 + tid*16 (linear).
    const int srow = tid >> 3;           // 0..31
    const int cgp  = tid & 7;
    const int cgl  = cgp ^ (srow & 7);

    const int8_t* gA = A + (size_t)(bm * BM + srow) * K_DIM + cgl * 16;
    const int8_t* gB = B + (size_t)(bn * BN + srow) * K_DIM + cgl * 16;
    const int lw = tid * 16;             // lds byte offset within buffer (+ p*4096)

    uint4 ra[4], rb[4];

    // Prologue: load tile0, write to buf0, then issue tile1 loads (stay in flight).
#pragma unroll
    for (int p = 0; p < 4; p++) {
        ra[p] = *(const uint4*)(gA + (size_t)p * 32 * K_DIM);
        rb[p] = *(const uint4*)(gB + (size_t)p * 32 * K_DIM);
    }
#pragma unroll
    for (int p = 0; p < 4; p++) {
        *(uint4*)(As + p * 4096 + lw) = ra[p];
        *(uint4*)(Bs + p * 4096 + lw) = rb[p];
    }
#pragma unroll
    for (int p = 0; p < 4; p++) {
        ra[p] = *(const uint4*)(gA + BK + (size_t)p * 32 * K_DIM);
        rb[p] = *(const uint4*)(gB + BK + (size_t)p * 32 * K_DIM);
    }
    __syncthreads();

    int4v acc[4][4] = {};

    int cur = 0;
    for (int k0 = 0; k0 < K_DIM; k0 += BK, cur ^= 1) {
        const int kn = k0 + BK;
        // Drain the register bridge: write tile (k0+BK) into the buffer consumed
        // last iteration (all waves passed the previous barrier -> safe), then
        // issue loads for tile (k0+2*BK).
        if (kn < K_DIM) {
            const int nb = cur ^ 1;
#pragma unroll
            for (int p = 0; p < 4; p++) {
                *(uint4*)(As + nb * ATILE + p * 4096 + lw) = ra[p];
                *(uint4*)(Bs + nb * BTILE + p * 4096 + lw) = rb[p];
            }
            if (kn + BK < K_DIM) {
#pragma unroll
                for (int p = 0; p < 4; p++) {
                    ra[p] = *(const uint4*)(gA + kn + BK + (size_t)p * 32 * K_DIM);
                    rb[p] = *(const uint4*)(gB + kn + BK + (size_t)p * 32 * K_DIM);
                }
            }
        }

        const int8_t* Ab = As + cur * ATILE;
        const int8_t* Bb = Bs + cur * BTILE;

#pragma unroll
        for (int s = 0; s < 2; s++) {
            const int cp = (s * 4 + quad) ^ swz;   // physical colgroup to read
            int4v af[4], bfr[4];
#pragma unroll
            for (int i = 0; i < 4; i++)
                af[i] = *(const int4v*)(Ab + (wm + i * 16 + l16) * BK + cp * 16);
#pragma unroll
            for (int j = 0; j < 4; j++)
                bfr[j] = *(const int4v*)(Bb + (wn + j * 16 + l16) * BK + cp * 16);
#pragma unroll
            for (int i = 0; i < 4; i++)
#pragma unroll
                for (int j = 0; j < 4; j++)
                    acc[i][j] = __builtin_amdgcn_mfma_i32_16x16x64_i8(
                        af[i], bfr[j], acc[i][j], 0, 0, 0);
        }

        __syncthreads();   // ds_writes to nb visible; frees cur for next write
    }

    // Row dequant scales for this lane's 16 output rows.
    float sxr[16];
#pragma unroll
    for (int i = 0; i < 4; i++)
#pragma unroll
        for (int r = 0; r < 4; r++)
            sxr[i * 4 + r] = sx[bm * BM + wm + i * 16 + quad * 4 + r];

    // Epilogue. C/D layout (shape-determined, verified): col = lane&15, row = quad*4 + reg.
#pragma unroll
    for (int j = 0; j < 4; j++) {
        const int col = bn * BN + wn + j * 16 + l16;
        const float s = scales[col];
        const float b = bias[col];
#pragma unroll
        for (int i = 0; i < 4; i++) {
            const int row0 = bm * BM + wm + i * 16 + quad * 4;
#pragma unroll
            for (int r = 0; r < 4; r++) {
                C[(size_t)(row0 + r) * N_DIM + col] =
                    (float)acc[i][j][r] * (sxr[i * 4 + r] * s) + b;
            }
        }
    }
}

// ---------- launch ----------

extern "C" void kernel_launch(void* const* d_in, const int* in_sizes, int n_in,
                              void* d_out, int out_size, void* d_ws, size_t ws_size,
                              hipStream_t stream) {
    const float* x      = (const float*)d_in[0];   // [2,1024,4096] fp32
    const int*   w      = (const int*)d_in[1];     // [4096,4096] int, values in [-128,127]
    const float* scales = (const float*)d_in[2];   // [4096]
    const float* bias   = (const float*)d_in[3];   // [4096]
    float*       out    = (float*)d_out;           // [2,1024,4096] fp32

    int8_t* Aq = (int8_t*)d_ws;                                        // 8 MiB
    int8_t* Bq = (int8_t*)d_ws + (size_t)M_DIM * K_DIM;                // 16 MiB
    float*  sx = (float*)((int8_t*)d_ws + (size_t)(M_DIM + N_DIM) * K_DIM); // 8 KiB

    quant_x<<<M_DIM, 256, 0, stream>>>(x, Aq, sx);
    cvt_w8<<<(int)((size_t)N_DIM * K_DIM / 16 / 256), 256, 0, stream>>>(w, Bq);

    dim3 grid(N_DIM / BN, M_DIM / BM);  // (32, 16) = 512 blocks = 2/CU
    gemm_bt_i8<<<grid, 256, 0, stream>>>(Aq, Bq, sx, scales, bias, out);
}

// Round 7
// 203.139 us; speedup vs baseline: 1.1699x; 1.1699x over previous
//
#include <hip/hip_runtime.h>
#include <hip/hip_bf16.h>
#include <stdint.h>

// Shape fixed by reference: B=2, S=1024 -> M=2048; N=4096; K=4096
#define M_DIM 2048
#define N_DIM 4096
#define K_DIM 4096

#define BM 128
#define BN 128
#define BK 128            // int8 elems per K-tile = 128 B per row

#define ATILE (BM * BK)   // 16 KiB per A buffer

typedef __attribute__((ext_vector_type(4))) int int4v;

__device__ __forceinline__ void load_lds16(const void* g, void* l) {
    __builtin_amdgcn_global_load_lds(
        (const __attribute__((address_space(1))) void*)g,
        (__attribute__((address_space(3))) void*)l,
        16, 0, 0);
}

// ---------- x: fp32 [M,K] -> int8 per-row dynamic quant; sx[row] = rowmax/127 ----------
__global__ __launch_bounds__(256) void quant_x(const float* __restrict__ x,
                                               int8_t* __restrict__ Aq,
                                               float* __restrict__ sx) {
    const int row = blockIdx.x;
    const int tid = threadIdx.x;
    const float4* xr = (const float4*)(x + (size_t)row * K_DIM);

    float4 v[4];
    float mx = 0.f;
#pragma unroll
    for (int p = 0; p < 4; p++) {
        v[p] = xr[p * 256 + tid];
        mx = fmaxf(mx, fmaxf(fmaxf(fabsf(v[p].x), fabsf(v[p].y)),
                             fmaxf(fabsf(v[p].z), fabsf(v[p].w))));
    }
#pragma unroll
    for (int off = 32; off >= 1; off >>= 1)
        mx = fmaxf(mx, __shfl_xor(mx, off, 64));

    __shared__ float wmax[4];
    __shared__ float smax;
    if ((tid & 63) == 0) wmax[tid >> 6] = mx;
    __syncthreads();
    if (tid == 0) {
        float m = fmaxf(fmaxf(wmax[0], wmax[1]), fmaxf(wmax[2], wmax[3]));
        m = fmaxf(m, 1e-20f);
        smax = m;
        sx[row] = m * (1.0f / 127.0f);
    }
    __syncthreads();
    const float inv = 127.0f / smax;

    int* out = (int*)Aq + (size_t)row * (K_DIM / 4);
#pragma unroll
    for (int p = 0; p < 4; p++) {
        int q0 = (int)__builtin_rintf(v[p].x * inv);
        int q1 = (int)__builtin_rintf(v[p].y * inv);
        int q2 = (int)__builtin_rintf(v[p].z * inv);
        int q3 = (int)__builtin_rintf(v[p].w * inv);
        q0 = max(-127, min(127, q0)); q1 = max(-127, min(127, q1));
        q2 = max(-127, min(127, q2)); q3 = max(-127, min(127, q3));
        out[p * 256 + tid] = (q0 & 255) | ((q1 & 255) << 8) |
                             ((q2 & 255) << 16) | ((q3 & 255) << 24);
    }
}

// ---------- w: int32 [N,K] (values in [-128,127]) -> int8 (low-byte, exact) ----------
__global__ __launch_bounds__(256) void cvt_w8(const int* __restrict__ w,
                                              int8_t* __restrict__ Bq) {
    size_t i = ((size_t)blockIdx.x * 256 + threadIdx.x) * 16;
    int4 a0 = *(const int4*)(w + i);
    int4 a1 = *(const int4*)(w + i + 4);
    int4 a2 = *(const int4*)(w + i + 8);
    int4 a3 = *(const int4*)(w + i + 12);
    uint4 t;
    t.x = (a0.x & 255) | ((a0.y & 255) << 8) | ((a0.z & 255) << 16) | ((a0.w & 255) << 24);
    t.y = (a1.x & 255) | ((a1.y & 255) << 8) | ((a1.z & 255) << 16) | ((a1.w & 255) << 24);
    t.z = (a2.x & 255) | ((a2.y & 255) << 8) | ((a2.z & 255) << 16) | ((a2.w & 255) << 24);
    t.w = (a3.x & 255) | ((a3.y & 255) << 8) | ((a3.z & 255) << 16) | ((a3.w & 255) << 24);
    *(uint4*)(Bq + i) = t;
}

// ---------- GEMM: C = Aq[M,K] x Bq[N,K]^T (i8 MFMA, i32 acc), dequant epilogue ----------
// Round-7: r4 skeleton (glds A-staging + dbuf + XOR swizzle: proven 0-conflict,
// no spills) with B REMOVED from LDS:
//  * 256 thr = 4 waves (2x2); wave tile 64x64 = acc[4][4] -> A-frag reads reused 4x.
//  * B fragments load straight global->VGPR (dwordx4; 16 rows x 64 B segments,
//    B is L2/L3-resident at 16 MB). Removes B's DMA writes + LDS frag reads.
//  * LDS traffic/CU-iter: 256 KiB (r4) -> 96 KiB; B moves to the L2 pipe (~64
//    KiB/CU-iter); MFMA ~1170 cyc/CU-iter. Three different pipes, now balanced.
//  * vmcnt ordering: B loads are issued BEFORE the glds A-prefetch each iter,
//    so waiting on B never waits on the A-tile DMA (oldest-first vmcnt).
//  * k-alignment: A's phase-s LDS frag covers logical k-bytes s*64+quad*16
//    (staging swizzle cancels against read swizzle); B direct loads use the
//    same offsets, so per-lane k-slots match and the i8 MFMA's internal lane->k
//    permutation cancels between A and B.

__global__ __launch_bounds__(256, 2) void gemm_bt_i8(
    const int8_t* __restrict__ A,      // [M,K] int8
    const int8_t* __restrict__ B,      // [N,K] int8
    const float*  __restrict__ sx,     // [M] row dequant scale
    const float*  __restrict__ scales, // [N]
    const float*  __restrict__ bias,   // [N]
    float* __restrict__ C)             // [M,N]
{
    __shared__ __align__(16) int8_t As[2 * ATILE];  // 32 KiB

    const int tid  = threadIdx.x;
    const int bm   = blockIdx.y;
    const int bn   = blockIdx.x;
    const int lane = tid & 63;
    const int wave = tid >> 6;           // 0..3
    const int wm   = (wave >> 1) * 64;   // 0 or 64
    const int wn   = (wave & 1) * 64;    // 0 or 64
    const int l16  = lane & 15;
    const int quad = lane >> 4;
    const int swz  = l16 & 7;

    // A staging: 256 thr x 16 B = 4 KiB per glds instr; 4 instrs cover the
    // 16 KiB tile (rows p*32 + srow). Logical colgroup cgl = cgp ^ (row&7);
    // (p*32+srow)&7 == srow&7, so cgl is uniform across p. LDS dst = p*4096 +
    // tid*16 (wave-uniform base + lane*16: glds layout rule).
    const int srow = tid >> 3;           // 0..31
    const int cgp  = tid & 7;
    const int cgl  = cgp ^ (srow & 7);

    const int8_t* gA = A + (size_t)(bm * BM + srow) * K_DIM + cgl * 16;
    const int lw = tid * 16;

    // B direct-load base: this lane's 4 rows are wn + j*16 + l16.
    const int8_t* gB = B + (size_t)(bn * BN + wn + l16) * K_DIM + quad * 16;

    // Prologue: stage A tile 0 into buffer 0.
#pragma unroll
    for (int p = 0; p < 4; p++)
        load_lds16(gA + (size_t)p * 32 * K_DIM, As + p * 4096 + lw);

    int4v acc[4][4] = {};

    int cur = 0;
    for (int k0 = 0; k0 < K_DIM; k0 += BK, cur ^= 1) {
        __syncthreads();   // drains glds for buf[cur]; all waves done with buf[cur^1]

        // Issue ALL B loads for this iteration first (younger than nothing,
        // older than the glds prefetch -> their waitcnt never waits on glds).
        int4v bl[2][4];
#pragma unroll
        for (int s = 0; s < 2; s++)
#pragma unroll
            for (int j = 0; j < 4; j++)
                bl[s][j] = *(const int4v*)(gB + (size_t)j * 16 * K_DIM + k0 + s * 64);

        const int kn = k0 + BK;
        if (kn < K_DIM) {  // glds prefetch of next A tile, in flight during compute
            const int nb = cur ^ 1;
#pragma unroll
            for (int p = 0; p < 4; p++)
                load_lds16(gA + kn + (size_t)p * 32 * K_DIM,
                           As + nb * ATILE + p * 4096 + lw);
        }

        const int8_t* Ab = As + cur * ATILE;

#pragma unroll
        for (int s = 0; s < 2; s++) {
            const int cp = (s * 4 + quad) ^ swz;   // physical colgroup to read
            int4v af[4];
#pragma unroll
            for (int i = 0; i < 4; i++)
                af[i] = *(const int4v*)(Ab + (wm + i * 16 + l16) * BK + cp * 16);
#pragma unroll
            for (int i = 0; i < 4; i++)
#pragma unroll
                for (int j = 0; j < 4; j++)
                    acc[i][j] = __builtin_amdgcn_mfma_i32_16x16x64_i8(
                        af[i], bl[s][j], acc[i][j], 0, 0, 0);
        }
    }

    // Row dequant scales for this lane's 16 output rows.
    float sxr[16];
#pragma unroll
    for (int i = 0; i < 4; i++)
#pragma unroll
        for (int r = 0; r < 4; r++)
            sxr[i * 4 + r] = sx[bm * BM + wm + i * 16 + quad * 4 + r];

    // Epilogue. C/D layout (shape-determined, verified): col = lane&15, row = quad*4 + reg.
#pragma unroll
    for (int j = 0; j < 4; j++) {
        const int col = bn * BN + wn + j * 16 + l16;
        const float s = scales[col];
        const float b = bias[col];
#pragma unroll
        for (int i = 0; i < 4; i++) {
            const int row0 = bm * BM + wm + i * 16 + quad * 4;
#pragma unroll
            for (int r = 0; r < 4; r++) {
                C[(size_t)(row0 + r) * N_DIM + col] =
                    (float)acc[i][j][r] * (sxr[i * 4 + r] * s) + b;
            }
        }
    }
}

// ---------- launch ----------

extern "C" void kernel_launch(void* const* d_in, const int* in_sizes, int n_in,
                              void* d_out, int out_size, void* d_ws, size_t ws_size,
                              hipStream_t stream) {
    const float* x      = (const float*)d_in[0];   // [2,1024,4096] fp32
    const int*   w      = (const int*)d_in[1];     // [4096,4096] int, values in [-128,127]
    const float* scales = (const float*)d_in[2];   // [4096]
    const float* bias   = (const float*)d_in[3];   // [4096]
    float*       out    = (float*)d_out;           // [2,1024,4096] fp32

    int8_t* Aq = (int8_t*)d_ws;                                        // 8 MiB
    int8_t* Bq = (int8_t*)d_ws + (size_t)M_DIM * K_DIM;                // 16 MiB
    float*  sx = (float*)((int8_t*)d_ws + (size_t)(M_DIM + N_DIM) * K_DIM); // 8 KiB

    quant_x<<<M_DIM, 256, 0, stream>>>(x, Aq, sx);
    cvt_w8<<<(int)((size_t)N_DIM * K_DIM / 16 / 256), 256, 0, stream>>>(w, Bq);

    dim3 grid(N_DIM / BN, M_DIM / BM);  // (32, 16) = 512 blocks = 2/CU
    gemm_bt_i8<<<grid, 256, 0, stream>>>(Aq, Bq, sx, scales, bias, out);
}

// Round 8
// 200.194 us; speedup vs baseline: 1.1871x; 1.0147x over previous
//
#include <hip/hip_runtime.h>
#include <hip/hip_bf16.h>
#include <stdint.h>

// Shape fixed by reference: B=2, S=1024 -> M=2048; N=4096; K=4096
#define M_DIM 2048
#define N_DIM 4096
#define K_DIM 4096

#define BM 128
#define BN 128
#define BK 128            // int8 elems per K-tile = 128 B per row

#define ATILE (BM * BK)   // 16 KiB per A buffer

typedef __attribute__((ext_vector_type(4))) int int4v;

__device__ __forceinline__ void load_lds16(const void* g, void* l) {
    __builtin_amdgcn_global_load_lds(
        (const __attribute__((address_space(1))) void*)g,
        (__attribute__((address_space(3))) void*)l,
        16, 0, 0);
}

// ---------- x: fp32 [M,K] -> int8 per-row dynamic quant; sx[row] = rowmax/127 ----------
__global__ __launch_bounds__(256) void quant_x(const float* __restrict__ x,
                                               int8_t* __restrict__ Aq,
                                               float* __restrict__ sx) {
    const int row = blockIdx.x;
    const int tid = threadIdx.x;
    const float4* xr = (const float4*)(x + (size_t)row * K_DIM);

    float4 v[4];
    float mx = 0.f;
#pragma unroll
    for (int p = 0; p < 4; p++) {
        v[p] = xr[p * 256 + tid];
        mx = fmaxf(mx, fmaxf(fmaxf(fabsf(v[p].x), fabsf(v[p].y)),
                             fmaxf(fabsf(v[p].z), fabsf(v[p].w))));
    }
#pragma unroll
    for (int off = 32; off >= 1; off >>= 1)
        mx = fmaxf(mx, __shfl_xor(mx, off, 64));

    __shared__ float wmax[4];
    __shared__ float smax;
    if ((tid & 63) == 0) wmax[tid >> 6] = mx;
    __syncthreads();
    if (tid == 0) {
        float m = fmaxf(fmaxf(wmax[0], wmax[1]), fmaxf(wmax[2], wmax[3]));
        m = fmaxf(m, 1e-20f);
        smax = m;
        sx[row] = m * (1.0f / 127.0f);
    }
    __syncthreads();
    const float inv = 127.0f / smax;

    int* out = (int*)Aq + (size_t)row * (K_DIM / 4);
#pragma unroll
    for (int p = 0; p < 4; p++) {
        int q0 = (int)__builtin_rintf(v[p].x * inv);
        int q1 = (int)__builtin_rintf(v[p].y * inv);
        int q2 = (int)__builtin_rintf(v[p].z * inv);
        int q3 = (int)__builtin_rintf(v[p].w * inv);
        q0 = max(-127, min(127, q0)); q1 = max(-127, min(127, q1));
        q2 = max(-127, min(127, q2)); q3 = max(-127, min(127, q3));
        out[p * 256 + tid] = (q0 & 255) | ((q1 & 255) << 8) |
                             ((q2 & 255) << 16) | ((q3 & 255) << 24);
    }
}

// ---------- w: int32 [N,K] (values in [-128,127]) -> int8 (low-byte, exact) ----------
__global__ __launch_bounds__(256) void cvt_w8(const int* __restrict__ w,
                                              int8_t* __restrict__ Bq) {
    size_t i = ((size_t)blockIdx.x * 256 + threadIdx.x) * 16;
    int4 a0 = *(const int4*)(w + i);
    int4 a1 = *(const int4*)(w + i + 4);
    int4 a2 = *(const int4*)(w + i + 8);
    int4 a3 = *(const int4*)(w + i + 12);
    uint4 t;
    t.x = (a0.x & 255) | ((a0.y & 255) << 8) | ((a0.z & 255) << 16) | ((a0.w & 255) << 24);
    t.y = (a1.x & 255) | ((a1.y & 255) << 8) | ((a1.z & 255) << 16) | ((a1.w & 255) << 24);
    t.z = (a2.x & 255) | ((a2.y & 255) << 8) | ((a2.z & 255) << 16) | ((a2.w & 255) << 24);
    t.w = (a3.x & 255) | ((a3.y & 255) << 8) | ((a3.z & 255) << 16) | ((a3.w & 255) << 24);
    *(uint4*)(Bq + i) = t;
}

// ---------- GEMM: C = Aq[M,K] x Bq[N,K]^T (i8 MFMA, i32 acc), dequant epilogue ----------
// Round-8: r7 layout (4 waves 2x2, wave tile 64x64, A in LDS via glds dbuf,
// B direct from L2) with r7's bug fixed: B is now DOUBLE-BUFFERED IN REGISTERS,
// prefetched one full iteration ahead (like the A glds dbuf), so no global
// latency is consumed in the iteration that issues it. K-loop unrolled x2 so
// the two B register banks are statically allocated (no dynamic reg indexing).
// At every __syncthreads, all outstanding vmem (A glds + B loads) was issued
// one compute phase (~500+ cyc) earlier -> the compiler's vmcnt(0) barrier
// drain is ~free. r6/r7 lesson: global data consumed in its issue-iteration
// = exposed latency; everything must be >=1 iteration ahead.
// Pipe balance per CU-iter (2 blocks/CU): LDS 96 KiB ~1130 cyc, MFMA ~1300 cyc,
// B-from-L2 32 KiB ~590 cyc -> MFMA-limited floor ~17.4 us.

__global__ __launch_bounds__(256, 2) void gemm_bt_i8(
    const int8_t* __restrict__ A,      // [M,K] int8
    const int8_t* __restrict__ B,      // [N,K] int8
    const float*  __restrict__ sx,     // [M] row dequant scale
    const float*  __restrict__ scales, // [N]
    const float*  __restrict__ bias,   // [N]
    float* __restrict__ C)             // [M,N]
{
    __shared__ __align__(16) int8_t As[2 * ATILE];  // 32 KiB

    const int tid  = threadIdx.x;
    const int bm   = blockIdx.y;
    const int bn   = blockIdx.x;
    const int lane = tid & 63;
    const int wave = tid >> 6;           // 0..3
    const int wm   = (wave >> 1) * 64;   // 0 or 64
    const int wn   = (wave & 1) * 64;    // 0 or 64
    const int l16  = lane & 15;
    const int quad = lane >> 4;
    const int swz  = l16 & 7;

    // A staging: 4 glds instrs of 256 thr x 16 B cover the 16 KiB tile.
    // LDS[row][cgp] = global[row][cgp ^ (row&7)]; read side undoes the XOR.
    const int srow = tid >> 3;           // 0..31
    const int cgp  = tid & 7;
    const int cgl  = cgp ^ (srow & 7);

    const int8_t* gA = A + (size_t)(bm * BM + srow) * K_DIM + cgl * 16;
    const int lw = tid * 16;

    // B direct-load base: lane's rows are wn + j*16 + l16, bytes quad*16 within
    // each 64 B phase segment.
    const int8_t* gB = B + (size_t)(bn * BN + wn + l16) * K_DIM + quad * 16;

    int4v acc[4][4] = {};
    int4v b0[2][4], b1[2][4];

    // Prologue: stage A tile 0 (buf0) + load B tile 0 into b0.
#pragma unroll
    for (int p = 0; p < 4; p++)
        load_lds16(gA + (size_t)p * 32 * K_DIM, As + p * 4096 + lw);
#pragma unroll
    for (int s = 0; s < 2; s++)
#pragma unroll
        for (int j = 0; j < 4; j++)
            b0[s][j] = *(const int4v*)(gB + (size_t)j * 16 * K_DIM + s * 64);

    auto compute = [&](const int8_t* Ab, int4v (&bb)[2][4]) {
#pragma unroll
        for (int s = 0; s < 2; s++) {
            const int cp = (s * 4 + quad) ^ swz;   // physical colgroup to read
            int4v af[4];
#pragma unroll
            for (int i = 0; i < 4; i++)
                af[i] = *(const int4v*)(Ab + (wm + i * 16 + l16) * BK + cp * 16);
#pragma unroll
            for (int i = 0; i < 4; i++)
#pragma unroll
                for (int j = 0; j < 4; j++)
                    acc[i][j] = __builtin_amdgcn_mfma_i32_16x16x64_i8(
                        af[i], bb[s][j], acc[i][j], 0, 0, 0);
        }
    };

    const int NIT = K_DIM / BK;          // 32 (even)
    for (int kd = 0; kd < NIT; kd += 2) {
        const int k1 = (kd + 1) * BK;    // always < K_DIM
        const int k2 = (kd + 2) * BK;

        // ---- even half: consume buf0/b0; prefetch k1 into buf1/b1 ----
        __syncthreads();                 // buf0 glds + b0 loads landed (issued 1 iter ago)
#pragma unroll
        for (int s = 0; s < 2; s++)
#pragma unroll
            for (int j = 0; j < 4; j++)
                b1[s][j] = *(const int4v*)(gB + (size_t)j * 16 * K_DIM + k1 + s * 64);
#pragma unroll
        for (int p = 0; p < 4; p++)
            load_lds16(gA + k1 + (size_t)p * 32 * K_DIM, As + ATILE + p * 4096 + lw);
        compute(As, b0);

        // ---- odd half: consume buf1/b1; prefetch k2 into buf0/b0 ----
        __syncthreads();
        if (k2 < K_DIM) {
#pragma unroll
            for (int s = 0; s < 2; s++)
#pragma unroll
                for (int j = 0; j < 4; j++)
                    b0[s][j] = *(const int4v*)(gB + (size_t)j * 16 * K_DIM + k2 + s * 64);
#pragma unroll
            for (int p = 0; p < 4; p++)
                load_lds16(gA + k2 + (size_t)p * 32 * K_DIM, As + p * 4096 + lw);
        }
        compute(As + ATILE, b1);
    }

    // Row dequant scales for this lane's 16 output rows.
    float sxr[16];
#pragma unroll
    for (int i = 0; i < 4; i++)
#pragma unroll
        for (int r = 0; r < 4; r++)
            sxr[i * 4 + r] = sx[bm * BM + wm + i * 16 + quad * 4 + r];

    // Epilogue. C/D layout (shape-determined, verified): col = lane&15, row = quad*4 + reg.
#pragma unroll
    for (int j = 0; j < 4; j++) {
        const int col = bn * BN + wn + j * 16 + l16;
        const float s = scales[col];
        const float b = bias[col];
#pragma unroll
        for (int i = 0; i < 4; i++) {
            const int row0 = bm * BM + wm + i * 16 + quad * 4;
#pragma unroll
            for (int r = 0; r < 4; r++) {
                C[(size_t)(row0 + r) * N_DIM + col] =
                    (float)acc[i][j][r] * (sxr[i * 4 + r] * s) + b;
            }
        }
    }
}

// ---------- launch ----------

extern "C" void kernel_launch(void* const* d_in, const int* in_sizes, int n_in,
                              void* d_out, int out_size, void* d_ws, size_t ws_size,
                              hipStream_t stream) {
    const float* x      = (const float*)d_in[0];   // [2,1024,4096] fp32
    const int*   w      = (const int*)d_in[1];     // [4096,4096] int, values in [-128,127]
    const float* scales = (const float*)d_in[2];   // [4096]
    const float* bias   = (const float*)d_in[3];   // [4096]
    float*       out    = (float*)d_out;           // [2,1024,4096] fp32

    int8_t* Aq = (int8_t*)d_ws;                                        // 8 MiB
    int8_t* Bq = (int8_t*)d_ws + (size_t)M_DIM * K_DIM;                // 16 MiB
    float*  sx = (float*)((int8_t*)d_ws + (size_t)(M_DIM + N_DIM) * K_DIM); // 8 KiB

    quant_x<<<M_DIM, 256, 0, stream>>>(x, Aq, sx);
    cvt_w8<<<(int)((size_t)N_DIM * K_DIM / 16 / 256), 256, 0, stream>>>(w, Bq);

    dim3 grid(N_DIM / BN, M_DIM / BM);  // (32, 16) = 512 blocks = 2/CU
    gemm_bt_i8<<<grid, 256, 0, stream>>>(Aq, Bq, sx, scales, bias, out);
}